// Round 8
// baseline (1552.049 us; speedup 1.0000x reference)
//
#include <hip/hip_runtime.h>
#include <math.h>

#define B_ 4
#define N_ 1024
#define C_ 1024
#define H_ 16
#define HD_ 64

// ---------------------------------------------------------------------------
// ERROR MODEL (validated r4/r6/r7: absmax 16 vs threshold 97):
//   S = (1-g)*spv/sp + g*sqv/sq ~ 4e-5 from cancellation; budget dS ~1.3e-7
//   => weight rel err <= 4e-8 for BOTH softmaxes -> f64 logits+exp
//   (fast_exp64, 3e-10). V_m exact via f64 wsum collapse. q,k <1e-7 ->
//   slab-f64 GEMM. DAMPED paths (PV numerators, v, proj): plain f32.
// PERF MODEL (r7 lesson): attn was LDS-pipe bound (~2600 LDS cyc/wave-tile
// vs ~2300 VALU, LDS shared per CU). r8: Q+qcoord via wave-uniform GLOBAL
// reads (scalarizable, off LDS pipe); PV remapped to (key-quarter, dim-quad)
// lanes -> pt/qt reads 128->32 b128/tile; LDS 45.5K->40K (4 blocks/CU).
// ---------------------------------------------------------------------------

// fast f64 exp for |a| <= ~16: range-reduce + deg-8 Taylor. rel err ~3e-10.
__device__ __forceinline__ double fast_exp64(double a) {
    const double LOG2E = 1.4426950408889634074;
    const double LN2HI = 6.93147180369123816490e-01;
    const double LN2LO = 1.90821492927058770002e-10;
    const double MAGIC = 6755399441055744.0;   // 1.5 * 2^52
    double t     = a * LOG2E;
    double shift = t + MAGIC;
    int    n     = (int)__double_as_longlong(shift);
    double nd    = shift - MAGIC;
    double f     = __fma_rn(nd, -LN2HI, a);
    f            = __fma_rn(nd, -LN2LO, f);
    double p = 2.4801587301587301587e-05;
    p = __fma_rn(p, f, 1.9841269841269841270e-04);
    p = __fma_rn(p, f, 1.3888888888888888889e-03);
    p = __fma_rn(p, f, 8.3333333333333333333e-03);
    p = __fma_rn(p, f, 4.1666666666666666667e-02);
    p = __fma_rn(p, f, 1.6666666666666666667e-01);
    p = __fma_rn(p, f, 5.0e-01);
    p = __fma_rn(p, f, 1.0);
    p = __fma_rn(p, f, 1.0);
    return p * __longlong_as_double(((long long)(1023 + n)) << 52);
}

__device__ __forceinline__ void fma4(float4& acc, float s, const float4& v) {
    acc.x = fmaf(s, v.x, acc.x);
    acc.y = fmaf(s, v.y, acc.y);
    acc.z = fmaf(s, v.z, acc.z);
    acc.w = fmaf(s, v.w, acc.w);
}

// ---------------------------------------------------------------------------
// Slab-compensated GEMM for q,k (O=2048). Tile 128x64, f32 slabs -> f64.
// ---------------------------------------------------------------------------
__global__ __launch_bounds__(256)
void gemm_qk_kernel(const float* __restrict__ A,
                    const float* __restrict__ W0,   // W_qk rows 0..2047
                    float* __restrict__ outq,
                    float* __restrict__ outk,
                    int M, int K)
{
    __shared__ float As[16][132];
    __shared__ float Ws[16][68];

    const int t  = threadIdx.x;
    const int m0 = blockIdx.y * 128;
    const int o0 = blockIdx.x * 64;
    const int ty = t >> 4;
    const int tx = t & 15;

    double acc[8][4];
    #pragma unroll
    for (int i = 0; i < 8; ++i)
        #pragma unroll
        for (int j = 0; j < 4; ++j) acc[i][j] = 0.0;

    for (int k0 = 0; k0 < K; k0 += 16) {
        #pragma unroll
        for (int i = 0; i < 2; ++i) {
            int vix = t + i * 256;
            int r   = vix >> 2;
            int c4  = vix & 3;
            const float4 a4 = *reinterpret_cast<const float4*>(&A[(size_t)(m0 + r) * K + k0 + c4 * 4]);
            As[c4 * 4 + 0][r] = a4.x;
            As[c4 * 4 + 1][r] = a4.y;
            As[c4 * 4 + 2][r] = a4.z;
            As[c4 * 4 + 3][r] = a4.w;
        }
        {
            int c  = t >> 2;
            int c4 = t & 3;
            const float4 w4 = *reinterpret_cast<const float4*>(&W0[(size_t)(o0 + c) * K + k0 + c4 * 4]);
            Ws[c4 * 4 + 0][c] = w4.x;
            Ws[c4 * 4 + 1][c] = w4.y;
            Ws[c4 * 4 + 2][c] = w4.z;
            Ws[c4 * 4 + 3][c] = w4.w;
        }
        __syncthreads();

        float sacc[8][4];
        #pragma unroll
        for (int i = 0; i < 8; ++i)
            #pragma unroll
            for (int j = 0; j < 4; ++j) sacc[i][j] = 0.f;

        #pragma unroll
        for (int kk = 0; kk < 16; ++kk) {
            float a[8], bb[4];
            *reinterpret_cast<float4*>(&a[0])  = *reinterpret_cast<const float4*>(&As[kk][ty * 8]);
            *reinterpret_cast<float4*>(&a[4])  = *reinterpret_cast<const float4*>(&As[kk][ty * 8 + 4]);
            *reinterpret_cast<float4*>(&bb[0]) = *reinterpret_cast<const float4*>(&Ws[kk][tx * 4]);
            #pragma unroll
            for (int i = 0; i < 8; ++i)
                #pragma unroll
                for (int j = 0; j < 4; ++j)
                    sacc[i][j] += a[i] * bb[j];
        }
        #pragma unroll
        for (int i = 0; i < 8; ++i)
            #pragma unroll
            for (int j = 0; j < 4; ++j) acc[i][j] += (double)sacc[i][j];
        __syncthreads();
    }

    int oo = o0 + tx * 4;
    float* dst = (oo < 1024) ? outq : outk;
    oo &= 1023;
    const int hh = oo >> 6, d0 = oo & 63;
    #pragma unroll
    for (int i = 0; i < 8; ++i) {
        int m = m0 + ty * 8 + i;
        int bb_ = m >> 10, n = m & 1023;
        float4 r0 = make_float4((float)acc[i][0], (float)acc[i][1],
                                (float)acc[i][2], (float)acc[i][3]);
        *reinterpret_cast<float4*>(&dst[((((size_t)bb_ * H_) + hh) * N_ + n) * HD_ + d0]) = r0;
    }
}

// ---------------------------------------------------------------------------
// Plain f32 GEMM, tile 128x128 (damped paths: v and proj).
// ---------------------------------------------------------------------------
template<int MODE>
__global__ __launch_bounds__(256)
void gemm128_kernel(const float* __restrict__ A,
                    const float* __restrict__ W0,
                    const float* __restrict__ bias,
                    float* __restrict__ out0,
                    int M, int O, int K)
{
    __shared__ float As[16][132];
    __shared__ float Ws[16][132];

    const int t  = threadIdx.x;
    const int m0 = blockIdx.y * 128;
    const int o0 = blockIdx.x * 128;
    const int ty = t >> 4;
    const int tx = t & 15;

    float acc[8][8];
    #pragma unroll
    for (int i = 0; i < 8; ++i)
        #pragma unroll
        for (int j = 0; j < 8; ++j) acc[i][j] = 0.f;

    for (int k0 = 0; k0 < K; k0 += 16) {
        #pragma unroll
        for (int i = 0; i < 2; ++i) {
            int vix = t + i * 256;
            int r   = vix >> 2;
            int c4  = vix & 3;
            const float4 a4 = *reinterpret_cast<const float4*>(&A[(size_t)(m0 + r) * K + k0 + c4 * 4]);
            As[c4 * 4 + 0][r] = a4.x;
            As[c4 * 4 + 1][r] = a4.y;
            As[c4 * 4 + 2][r] = a4.z;
            As[c4 * 4 + 3][r] = a4.w;
        }
        #pragma unroll
        for (int i = 0; i < 2; ++i) {
            int vix = t + i * 256;
            int c   = vix >> 2;
            int c4  = vix & 3;
            const float4 w4 = *reinterpret_cast<const float4*>(&W0[(size_t)(o0 + c) * K + k0 + c4 * 4]);
            Ws[c4 * 4 + 0][c] = w4.x;
            Ws[c4 * 4 + 1][c] = w4.y;
            Ws[c4 * 4 + 2][c] = w4.z;
            Ws[c4 * 4 + 3][c] = w4.w;
        }
        __syncthreads();

        #pragma unroll
        for (int kk = 0; kk < 16; ++kk) {
            float a[8], bb[8];
            *reinterpret_cast<float4*>(&a[0])  = *reinterpret_cast<const float4*>(&As[kk][ty * 8]);
            *reinterpret_cast<float4*>(&a[4])  = *reinterpret_cast<const float4*>(&As[kk][ty * 8 + 4]);
            *reinterpret_cast<float4*>(&bb[0]) = *reinterpret_cast<const float4*>(&Ws[kk][tx * 8]);
            *reinterpret_cast<float4*>(&bb[4]) = *reinterpret_cast<const float4*>(&Ws[kk][tx * 8 + 4]);
            #pragma unroll
            for (int i = 0; i < 8; ++i)
                #pragma unroll
                for (int j = 0; j < 8; ++j)
                    acc[i][j] += a[i] * bb[j];
        }
        __syncthreads();
    }

    if (MODE == 1) {
        float bs[8];
        *reinterpret_cast<float4*>(&bs[0]) = *reinterpret_cast<const float4*>(&bias[o0 + tx * 8]);
        *reinterpret_cast<float4*>(&bs[4]) = *reinterpret_cast<const float4*>(&bias[o0 + tx * 8 + 4]);
        #pragma unroll
        for (int i = 0; i < 8; ++i) {
            int m = m0 + ty * 8 + i;
            float* p = &out0[(size_t)m * O + o0 + tx * 8];
            float4 r0 = make_float4(acc[i][0] + bs[0], acc[i][1] + bs[1], acc[i][2] + bs[2], acc[i][3] + bs[3]);
            float4 r1 = make_float4(acc[i][4] + bs[4], acc[i][5] + bs[5], acc[i][6] + bs[6], acc[i][7] + bs[7]);
            *reinterpret_cast<float4*>(p)     = r0;
            *reinterpret_cast<float4*>(p + 4) = r1;
        }
    } else {
        int oo = o0 + tx * 8;
        const int hh = oo >> 6, d0 = oo & 63;
        #pragma unroll
        for (int i = 0; i < 8; ++i) {
            int m = m0 + ty * 8 + i;
            int bb_ = m >> 10, n = m & 1023;
            float* p = &out0[((((size_t)bb_ * H_) + hh) * N_ + n) * HD_ + d0];
            *reinterpret_cast<float4*>(p)     = make_float4(acc[i][0], acc[i][1], acc[i][2], acc[i][3]);
            *reinterpret_cast<float4*>(p + 4) = make_float4(acc[i][4], acc[i][5], acc[i][6], acc[i][7]);
        }
    }
}

// ---------------------------------------------------------------------------
__global__ void wsum_kernel(const float* __restrict__ W_v, double* __restrict__ wsh)
{
    const int k = blockIdx.x * 256 + threadIdx.x;
    const int h = blockIdx.y;
    double s = 0.0;
    #pragma unroll 8
    for (int d = 0; d < 64; ++d) s += (double)W_v[(size_t)(h * 64 + d) * C_ + k];
    wsh[h * C_ + k] = s;
}

__global__ __launch_bounds__(256)
void vall_kernel(const float* __restrict__ x, const double* __restrict__ wsh,
                 double* __restrict__ Vall)
{
    __shared__ double ws_s[1024];
    const int h = blockIdx.y, b = blockIdx.z;
    const int m = blockIdx.x * 256 + threadIdx.x;
    for (int i = threadIdx.x; i < 1024; i += 256) ws_s[i] = wsh[h * C_ + i];
    __syncthreads();
    const float* xr = x + ((size_t)b * N_ + m) * C_;
    double acc = 0.0;
    #pragma unroll 8
    for (int kk = 0; kk < 1024; ++kk) acc += (double)xr[kk] * ws_s[kk];
    Vall[((size_t)b * H_ + h) * N_ + m] = acc;
}

// ---------------------------------------------------------------------------
// Fused attention r8: r7 double-buffered pipeline, LDS traffic minimized.
//  - Q + query coords: wave-uniform GLOBAL reads (off the LDS pipe).
//  - PV lane remap: lane=(kq=l>>4 key-quarter, dq=l&15 dim-quad) ->
//    pt/qt reads 32 b128/tile (was 128), V as dwordx4 (16/tile).
//  - LDS: Kt4 dbuf 32KB + pt/qt 8KB = 40960B.
// ---------------------------------------------------------------------------
__global__ __launch_bounds__(256)
void attn_kernel(const float* __restrict__ q,
                 const float* __restrict__ k,
                 const float* __restrict__ v,
                 const double* __restrict__ Vall,   // [B][H][N]
                 const float* __restrict__ coord,   // [B][N][3]
                 const float* __restrict__ W_pos,   // [H][4]
                 const float* __restrict__ gating,  // [H]
                 float* __restrict__ attn_out)      // [B][N][C]
{
    __shared__ float4 Kt4[2][64][16];              // 32KB double-buffered K
    __shared__ __align__(16) float pt[16][64];     // 4KB (wave-private rows)
    __shared__ __align__(16) float qt[16][64];     // 4KB

    const int t  = threadIdx.x;
    const int wu = __builtin_amdgcn_readfirstlane(t >> 6);  // wave id, SGPR
    const int l  = t & 63;
    const int kq = l >> 4;     // PV key-quarter
    const int dq = l & 15;     // PV dim-quad (dims 4dq..4dq+3)
    const int n0 = blockIdx.x * 16;
    const int h  = blockIdx.y;
    const int b  = blockIdx.z;
    const size_t bhN = ((size_t)b * H_ + h) * N_;

    // staging indices (4 vectors/tile/thread)
    const int sr0 = t >> 4;
    const int sc  = t & 15;

    // wave-uniform Q row pointers + query coords (global, scalarizable)
    const float4* qr0 = reinterpret_cast<const float4*>(q + (bhN + n0 + wu     ) * HD_);
    const float4* qr1 = reinterpret_cast<const float4*>(q + (bhN + n0 + wu + 4 ) * HD_);
    const float4* qr2 = reinterpret_cast<const float4*>(q + (bhN + n0 + wu + 8 ) * HD_);
    const float4* qr3 = reinterpret_cast<const float4*>(q + (bhN + n0 + wu + 12) * HD_);
    double qcx[4], qcy[4], qcz[4];
    #pragma unroll
    for (int i = 0; i < 4; ++i) {
        const float* cp = coord + ((size_t)b * N_ + n0 + wu + 4 * i) * 3;
        qcx[i] = (double)cp[0];
        qcy[i] = (double)cp[1];
        qcz[i] = (double)cp[2];
    }
    const double w4hd = (double)W_pos[h * 4 + 3];
    const double ghd  = 1.0 / (1.0 + exp(-(double)gating[h]));

    double sp[4], sq[4], spv[4], sqv[4];
    float4 accp4[4], accq4[4];
    #pragma unroll
    for (int i = 0; i < 4; ++i) {
        sp[i] = 0.0; sq[i] = 0.0; spv[i] = 0.0; sqv[i] = 0.0;
        accp4[i] = make_float4(0.f, 0.f, 0.f, 0.f);
        accq4[i] = make_float4(0.f, 0.f, 0.f, 0.f);
    }

    // ---- prologue: stage tile 0 + its Vm/coord
    {
        const float4* kb4 = reinterpret_cast<const float4*>(k + bhN * HD_);
        #pragma unroll
        for (int i = 0; i < 4; ++i)
            Kt4[0][sr0 + i * 16][sc ^ ((sr0 + i * 16) & 15)] = kb4[t + i * 256];
    }
    double Vm  = Vall[bhN + l];
    double cmx = (double)coord[((size_t)b * N_ + l) * 3 + 0];
    double cmy = (double)coord[((size_t)b * N_ + l) * 3 + 1];
    double cmz = (double)coord[((size_t)b * N_ + l) * 3 + 2];
    __syncthreads();

    for (int t16 = 0; t16 < 16; ++t16) {
        const int cur = t16 & 1;
        const int m0  = t16 * 64;

        // ---- (1) issue next tile's loads
        float4 st0, st1, st2, st3;
        double VmN = 0.0, cmxN = 0.0, cmyN = 0.0, cmzN = 0.0;
        if (t16 < 15) {
            const float4* kb4 = reinterpret_cast<const float4*>(k + (bhN + m0 + 64) * HD_);
            st0 = kb4[t];
            st1 = kb4[t + 256];
            st2 = kb4[t + 512];
            st3 = kb4[t + 768];
            VmN  = Vall[bhN + m0 + 64 + l];
            cmxN = (double)coord[((size_t)b * N_ + m0 + 64 + l) * 3 + 0];
            cmyN = (double)coord[((size_t)b * N_ + m0 + 64 + l) * 3 + 1];
            cmzN = (double)coord[((size_t)b * N_ + m0 + 64 + l) * 3 + 2];
        }

        // ---- (2) QK^T from Kt4[cur] + Q via uniform global reads
        float dotp[4][4];
        #pragma unroll
        for (int i = 0; i < 4; ++i)
            #pragma unroll
            for (int g = 0; g < 4; ++g) dotp[i][g] = 0.f;
        #pragma unroll
        for (int d4 = 0; d4 < 16; ++d4) {
            const float4 kt = Kt4[cur][l][d4 ^ (l & 15)];
            const int g = d4 >> 2;
            const float4 q0 = qr0[d4];
            const float4 q1 = qr1[d4];
            const float4 q2 = qr2[d4];
            const float4 q3 = qr3[d4];
            float s0 = dotp[0][g], s1 = dotp[1][g], s2 = dotp[2][g], s3 = dotp[3][g];
            s0 = fmaf(kt.x, q0.x, s0); s0 = fmaf(kt.y, q0.y, s0);
            s0 = fmaf(kt.z, q0.z, s0); s0 = fmaf(kt.w, q0.w, s0);
            s1 = fmaf(kt.x, q1.x, s1); s1 = fmaf(kt.y, q1.y, s1);
            s1 = fmaf(kt.z, q1.z, s1); s1 = fmaf(kt.w, q1.w, s1);
            s2 = fmaf(kt.x, q2.x, s2); s2 = fmaf(kt.y, q2.y, s2);
            s2 = fmaf(kt.z, q2.z, s2); s2 = fmaf(kt.w, q2.w, s2);
            s3 = fmaf(kt.x, q3.x, s3); s3 = fmaf(kt.y, q3.y, s3);
            s3 = fmaf(kt.z, q3.z, s3); s3 = fmaf(kt.w, q3.w, s3);
            dotp[0][g] = s0; dotp[1][g] = s1; dotp[2][g] = s2; dotp[3][g] = s3;
        }

        // ---- (3) f64 weights + S-path updates (lane = m = m0+l)
        #pragma unroll
        for (int i = 0; i < 4; ++i) {
            const int r = wu + 4 * i;
            const double lg = (((double)dotp[i][0] + (double)dotp[i][1]) +
                               ((double)dotp[i][2] + (double)dotp[i][3])) * 0.125;
            const double p64 = fast_exp64(lg);
            const double dx = qcx[i] - cmx;
            const double dy = qcy[i] - cmy;
            const double dz = qcz[i] - cmz;
            const double r2 = __fma_rn(dx, dx, __fma_rn(dy, dy, dz * dz));
            const double y0 = (double)rsqrtf((float)r2);
            const double y1 = y0 * __fma_rn(-0.5 * r2, y0 * y0, 1.5);
            const double dist = (r2 > 0.0) ? r2 * y1 : 0.0;
            const double q64 = fast_exp64(dist * w4hd);
            pt[r][l] = (float)p64;
            qt[r][l] = (float)q64;
            sp[i]  += p64;
            sq[i]  += q64;
            spv[i] += p64 * Vm;
            sqv[i] += q64 * Vm;
        }

        // ---- (4) PV: lane (kq,dq) covers keys kq*16..+15, dims 4dq..+3
        const float4* vquad = reinterpret_cast<const float4*>(v + (bhN + m0 + kq * 16) * HD_) + dq;
        #pragma unroll
        for (int mc = 0; mc < 4; ++mc) {
            const int mb = mc * 4;
            const float4 v0 = vquad[(mb + 0) * 16];
            const float4 v1 = vquad[(mb + 1) * 16];
            const float4 v2 = vquad[(mb + 2) * 16];
            const float4 v3 = vquad[(mb + 3) * 16];
            #pragma unroll
            for (int i = 0; i < 4; ++i) {
                const float4 pp = *reinterpret_cast<const float4*>(&pt[wu + 4 * i][kq * 16 + mb]);
                const float4 pq = *reinterpret_cast<const float4*>(&qt[wu + 4 * i][kq * 16 + mb]);
                fma4(accp4[i], pp.x, v0); fma4(accp4[i], pp.y, v1);
                fma4(accp4[i], pp.z, v2); fma4(accp4[i], pp.w, v3);
                fma4(accq4[i], pq.x, v0); fma4(accq4[i], pq.y, v1);
                fma4(accq4[i], pq.z, v2); fma4(accq4[i], pq.w, v3);
            }
        }

        // ---- (5) write staged K into other buffer; roll Vm/coord
        if (t16 < 15) {
            const int nxt = cur ^ 1;
            Kt4[nxt][sr0     ][sc ^ ( sr0       & 15)] = st0;
            Kt4[nxt][sr0 + 16][sc ^ ((sr0 + 16) & 15)] = st1;
            Kt4[nxt][sr0 + 32][sc ^ ((sr0 + 32) & 15)] = st2;
            Kt4[nxt][sr0 + 48][sc ^ ((sr0 + 48) & 15)] = st3;
            Vm = VmN; cmx = cmxN; cmy = cmyN; cmz = cmzN;
        }
        // ---- (6) single barrier per tile
        __syncthreads();
    }

    // ---- epilogue ----
    // 1) complete PV sums across the 4 key-quarters
    #pragma unroll
    for (int i = 0; i < 4; ++i) {
        #pragma unroll
        for (int mask = 16; mask <= 32; mask <<= 1) {
            accp4[i].x += __shfl_xor(accp4[i].x, mask);
            accp4[i].y += __shfl_xor(accp4[i].y, mask);
            accp4[i].z += __shfl_xor(accp4[i].z, mask);
            accp4[i].w += __shfl_xor(accp4[i].w, mask);
            accq4[i].x += __shfl_xor(accq4[i].x, mask);
            accq4[i].y += __shfl_xor(accq4[i].y, mask);
            accq4[i].z += __shfl_xor(accq4[i].z, mask);
            accq4[i].w += __shfl_xor(accq4[i].w, mask);
        }
    }
    // 2) f64 reduce of S-path sums; per-row scalars
    double w1a[4], w2a[4], Sa[4];
    #pragma unroll
    for (int i = 0; i < 4; ++i) {
        double vsp = sp[i], vsq = sq[i], vspv = spv[i], vsqv = sqv[i];
        #pragma unroll
        for (int mm = 32; mm >= 1; mm >>= 1) {
            vsp  += __shfl_xor(vsp,  mm);
            vsq  += __shfl_xor(vsq,  mm);
            vspv += __shfl_xor(vspv, mm);
            vsqv += __shfl_xor(vsqv, mm);
        }
        w1a[i] = (1.0 - ghd) / vsp;
        w2a[i] = ghd / vsq;
        Sa[i]  = w1a[i] * vspv + w2a[i] * vsqv;
    }
    // 3) lane (kq,dq) stores row wu+4*kq, dims 4dq..4dq+3
    float4 ap = accp4[0], aq = accq4[0];
    double w1g = w1a[0], w2g = w2a[0], Sg = Sa[0];
    if (kq == 1) { ap = accp4[1]; aq = accq4[1]; w1g = w1a[1]; w2g = w2a[1]; Sg = Sa[1]; }
    if (kq == 2) { ap = accp4[2]; aq = accq4[2]; w1g = w1a[2]; w2g = w2a[2]; Sg = Sa[2]; }
    if (kq == 3) { ap = accp4[3]; aq = accq4[3]; w1g = w1a[3]; w2g = w2a[3]; Sg = Sa[3]; }
    const double inv = 1.0 / Sg;
    float4 o;
    o.x = (float)((w1g * (double)ap.x + w2g * (double)aq.x) * inv);
    o.y = (float)((w1g * (double)ap.y + w2g * (double)aq.y) * inv);
    o.z = (float)((w1g * (double)ap.z + w2g * (double)aq.z) * inv);
    o.w = (float)((w1g * (double)ap.w + w2g * (double)aq.w) * inv);
    *reinterpret_cast<float4*>(&attn_out[((size_t)b * N_ + n0 + wu + 4 * kq) * C_ + h * HD_ + 4 * dq]) = o;
}

// ---------------------------------------------------------------------------
extern "C" void kernel_launch(void* const* d_in, const int* in_sizes, int n_in,
                              void* d_out, int out_size, void* d_ws, size_t ws_size,
                              hipStream_t stream)
{
    const float* x      = (const float*)d_in[0];
    const float* coord  = (const float*)d_in[1];
    const float* W_qk   = (const float*)d_in[2];
    const float* W_v    = (const float*)d_in[3];
    const float* W_proj = (const float*)d_in[4];
    const float* b_proj = (const float*)d_in[5];
    const float* W_pos  = (const float*)d_in[6];
    // d_in[7] = b_pos (cancels in softmax), d_in[9] = pos_emb (cancels) — unused
    const float* gating = (const float*)d_in[8];

    float* ws   = (float*)d_ws;
    const size_t per = (size_t)B_ * H_ * N_ * HD_;   // 4,194,304 floats
    float*  qb   = ws;
    float*  kb   = qb + per;
    float*  vb   = kb + per;
    float*  attn = vb + per;
    double* wsh  = (double*)(attn + per);
    double* Vall = wsh + (size_t)H_ * C_;
    float*  out  = (float*)d_out;

    wsum_kernel<<<dim3(4, 16), 256, 0, stream>>>(W_v, wsh);
    vall_kernel<<<dim3(4, 16, 4), 256, 0, stream>>>(x, wsh, Vall);

    gemm_qk_kernel<<<dim3(32, 32), 256, 0, stream>>>(x, W_qk, qb, kb, B_ * N_, C_);
    gemm128_kernel<0><<<dim3(8, 32), 256, 0, stream>>>(x, W_v, nullptr, vb, B_ * N_, C_, C_);

    attn_kernel<<<dim3(N_ / 16, H_, B_), 256, 0, stream>>>(
        qb, kb, vb, Vall, coord, W_pos, gating, attn);

    gemm128_kernel<1><<<dim3(8, 32), 256, 0, stream>>>(
        attn, W_proj, b_proj, out, B_ * N_, C_, C_);
}